// Round 20
// baseline (56.073 us; speedup 1.0000x reference)
//
#include <hip/hip_runtime.h>

#define HH 128
#define WW 128
#define CCH 128
#define NKD 21
#define RAD 10
#define ROWH 32                  // halves per tgt-image row (32c) = 64B
#define CH_HALVES (148 * ROWH)   // 4736 halves per chunk (148 p-rows)
#define CH_BYTES  (CH_HALVES * 2)        // 9472 B
#define IMG_HALVES (4 * CH_HALVES)       // 18944 halves per (b,i2) = 37888 B
#define SRC_HALVES 16384         // src image per (b,h): 128w x 128c halves = 32KB
#define SO_STRIDE 66             // s_o row stride (floats)
#define SO_WAVE   2112           // floats per wave slab (32*66)

typedef _Float16 f16x8 __attribute__((ext_vector_type(8)));
typedef float    f32x4 __attribute__((ext_vector_type(4)));
typedef __fp16   h2f   __attribute__((ext_vector_type(2)));

union PK { uint4 u; h2f h[4]; };

// --- kernel 1 (fused): n<512 -> tgt image [b][i2][chunk][p][32c];
//                       n>=512 -> src image [b][h][w][c] f16 (x 1/128 folded in) ---
__global__ __launch_bounds__(256)
void pack_all(const float* __restrict__ in, __fp16* __restrict__ img_tgt,
              __fp16* __restrict__ img_src) {
    int n = blockIdx.x;                 // 1024
    int tid = threadIdx.x;
    __shared__ __align__(16) char sraw[4 * CH_BYTES];   // used by tgt path only

    if (n < 512) {                      // ---- tgt image (b, i2) ----
        int b = n >> 7, i2 = n & 127;
        {   // zero-fill (covers p<10, p>137 pad rows)
            uint4 z = make_uint4(0, 0, 0, 0);
            uint4* sp = (uint4*)sraw;
#pragma unroll
            for (int k = 0; k < 9; ++k) sp[k * 256 + tid] = z;
            if (tid < 64) sp[9 * 256 + tid] = z;
        }
        __syncthreads();
        const float* tg = in + (size_t)(b * 2 + 1) * CCH * HH * WW + (size_t)i2 * WW;
        int w = tid & 127, half = tid >> 7;
        int p = w + RAD;                // 10..137
#pragma unroll
        for (int c2 = 0; c2 < 2; ++c2) {
            int cc = half * 2 + c2;     // chunk 0..3 (32 channels each)
#pragma unroll
            for (int g = 0; g < 4; ++g) {
                float v[8];
#pragma unroll
                for (int j = 0; j < 8; ++j)
                    v[j] = tg[(size_t)(cc * 32 + g * 8 + j) * (HH * WW) + w];
                PK q;
                q.h[0] = __builtin_amdgcn_cvt_pkrtz(v[0], v[1]);
                q.h[1] = __builtin_amdgcn_cvt_pkrtz(v[2], v[3]);
                q.h[2] = __builtin_amdgcn_cvt_pkrtz(v[4], v[5]);
                q.h[3] = __builtin_amdgcn_cvt_pkrtz(v[6], v[7]);
                *(uint4*)(sraw + (size_t)cc * CH_BYTES + p * 64 + g * 16) = q.u;
            }
        }
        __syncthreads();
        uint4* gi = (uint4*)(img_tgt + (size_t)n * IMG_HALVES);   // 2368 uint4
        const uint4* si = (const uint4*)sraw;
#pragma unroll
        for (int k = 0; k < 9; ++k) gi[k * 256 + tid] = si[k * 256 + tid];
        if (tid < 64) gi[9 * 256 + tid] = si[9 * 256 + tid];
    } else {                            // ---- src image (b, h), x 1/128 ----
        int m = n - 512;
        int b = m >> 7, h = m & 127;
        const float* src = in + (size_t)(b * 2) * CCH * HH * WW + (size_t)h * WW;
        __fp16* gi = img_src + (size_t)m * SRC_HALVES;
        const float sc = 1.f / 128.f;
        int w = tid & 127, half = tid >> 7;
#pragma unroll
        for (int t8 = 0; t8 < 8; ++t8) {
            int t = half * 8 + t8;      // c-block 0..15
            float v[8];
#pragma unroll
            for (int j = 0; j < 8; ++j)
                v[j] = src[(size_t)(t * 8 + j) * (HH * WW) + w] * sc;
            PK q;
            q.h[0] = __builtin_amdgcn_cvt_pkrtz(v[0], v[1]);
            q.h[1] = __builtin_amdgcn_cvt_pkrtz(v[2], v[3]);
            q.h[2] = __builtin_amdgcn_cvt_pkrtz(v[4], v[5]);
            q.h[3] = __builtin_amdgcn_cvt_pkrtz(v[6], v[7]);
            *(uint4*)&gi[w * 128 + t * 8] = q.u;   // [w][c] halves, c-contiguous
        }
    }
}

// -------- kernel 2: 2-row block, dy-split-2, ZERO-barrier, phase-rotated --------
// a-frags: 16 direct b128 loads from packed src image (fragment-order layout).
// B-frags: depth-4 register ring from packed tgt image. LDS = s_o only.
// MFMA: a (w-rows) FIRST, bfr (p-cols) SECOND -> acc rows=w(4g+j), cols=p(r).
__global__ __launch_bounds__(256, 2)
void corr_mfma(const __fp16* __restrict__ img_src, const __fp16* __restrict__ img_tgt,
               float* __restrict__ out) {
    int n = blockIdx.x;                 // 512
    int xcd = n & 7, idx = n >> 3;      // idx 0..63
    int u = xcd * 64 + idx;             // d-blocks of a pair adjacent on one XCD
    int d = u & 1;                      // dy-split half
    int hpair = u >> 1;                 // 0..255
    int b = hpair >> 6;                 // 0..3
    int h0 = (hpair & 63) << 1;         // even row base

    __shared__ __align__(16) float s_o[4 * SO_WAVE];   // 33792 B, wave-private slabs

    int tid = threadIdx.x;
    int q = tid >> 6, lane = tid & 63, r = lane & 15, g = lane >> 4;

    const char* imgb = (const char*)(img_tgt + (size_t)(b * 128) * IMG_HALVES);
    const int hbase = h0 + d * 11;      // hp = hbase + phl_a
    const int phl0 = (2178 - h0) % 11;  // phase rotation for instantaneous L2 sharing

    // ---- a-fragments: direct loads from src image (no LDS, no barriers) ----
    f16x8 a[2][2][4];   // [row][wi][ks]
#pragma unroll
    for (int row = 0; row < 2; ++row) {
        const char* srcb = (const char*)(img_src
                           + (size_t)(b * 128 + h0 + row) * SRC_HALVES);
#pragma unroll
        for (int wi = 0; wi < 2; ++wi) {
            int wrow = (2 * q + wi) * 16 + r;
#pragma unroll
            for (int ks = 0; ks < 4; ++ks)
                a[row][wi][ks] = *(const f16x8*)(srcb + wrow * 256 + ks * 64 + g * 16);
        }
    }

    // ---- static per-thread byte offsets within a tgt chunk (clamped band rows) ----
    int off[4];
#pragma unroll
    for (int pi = 0; pi < 4; ++pi) {
        int prow = (2 * q + pi) * 16 + r;
        if (prow > 147) prow = 147;
        off[pi] = prow * 64 + g * 16;
    }

    float* outb = out + (size_t)b * (NKD * NKD) * (HH * WW) + (size_t)h0 * WW;
    float* so = s_o + q * SO_WAVE;

    auto chunk_base = [&](int phl_a) -> const char* {
        int hp = hbase + phl_a;
        if (hp < RAD || hp > 137) return nullptr;
        return imgb + (size_t)(hp - RAD) * (IMG_HALVES * 2);
    };

    // DEPTH-4 register ring; phase holds its 4 chunks in buf[0..3] (slot = cc).
    uint4 buf[4][4];
    {
        const char* cb = chunk_base(phl0);
        if (cb) {
#pragma unroll
            for (int c0 = 0; c0 < 4; ++c0)
#pragma unroll
                for (int pi = 0; pi < 4; ++pi)
                    buf[c0][pi] = *(const uint4*)(cb + c0 * CH_BYTES + off[pi]);
        }
    }

    for (int it = 0; it < 11; ++it) {
        int phl_a = phl0 + it; if (phl_a >= 11) phl_a -= 11;
        int ph_g = d * 11 + phl_a;
        int row0_on = (ph_g <= 20);
        int row1_on = (ph_g >= 1);
        bool cur_ok = (chunk_base(phl_a) != nullptr);

        const char* nxt = nullptr;
        if (it + 1 < 11) {
            int phl_n = phl_a + 1; if (phl_n >= 11) phl_n -= 11;
            nxt = chunk_base(phl_n);
        }

        f32x4 acc[2][2][3];   // [row][wi][pj]
#pragma unroll
        for (int row = 0; row < 2; ++row)
#pragma unroll
            for (int wi = 0; wi < 2; ++wi)
#pragma unroll
                for (int pj = 0; pj < 3; ++pj)
#pragma unroll
                    for (int j = 0; j < 4; ++j) acc[row][wi][pj][j] = 0.f;

#pragma unroll
        for (int cc = 0; cc < 4; ++cc) {
            f16x8 bfr[4];
#pragma unroll
            for (int pi = 0; pi < 4; ++pi)
                bfr[pi] = __builtin_bit_cast(f16x8, buf[cc][pi]);

            if (nxt) {   // prefetch next phase's cc-chunk into the slot just consumed
#pragma unroll
                for (int pi = 0; pi < 4; ++pi)
                    buf[cc][pi] = *(const uint4*)(nxt + cc * CH_BYTES + off[pi]);
            }

            if (cur_ok && row0_on) {
#pragma unroll
                for (int wi = 0; wi < 2; ++wi)
#pragma unroll
                    for (int pj = 0; pj < 3; ++pj)
                        acc[0][wi][pj] = __builtin_amdgcn_mfma_f32_16x16x32_f16(
                            a[0][wi][cc], bfr[wi + pj], acc[0][wi][pj], 0, 0, 0);
            }
            if (cur_ok && row1_on) {
#pragma unroll
                for (int wi = 0; wi < 2; ++wi)
#pragma unroll
                    for (int pj = 0; pj < 3; ++pj)
                        acc[1][wi][pj] = __builtin_amdgcn_mfma_f32_16x16x32_f16(
                            a[1][wi][cc], bfr[wi + pj], acc[1][wi][pj], 0, 0, 0);
            }
        }

        // ---- staggered epilogues: row0 dy=ph_g, row1 dy=ph_g-1 (s_o wave-private) ----
#pragma unroll
        for (int row = 0; row < 2; ++row) {
            int dy = ph_g - row;
            if ((row == 0 && !row0_on) || (row == 1 && !row1_on)) continue;
#pragma unroll
            for (int wi = 0; wi < 2; ++wi)
#pragma unroll
                for (int pj = 0; pj < 3; ++pj)
#pragma unroll
                    for (int j = 0; j < 4; ++j)
                        so[(wi * 16 + 4 * g + j) * SO_STRIDE + (wi + pj) * 16 + r]
                            = acc[row][wi][pj][j];
            asm volatile("s_waitcnt lgkmcnt(0)" ::: "memory");
            __builtin_amdgcn_sched_barrier(0);
            float* op = outb + (size_t)row * WW + (size_t)dy * NKD * (HH * WW);
#pragma unroll
            for (int k = 0; k < 3; ++k) {
                int f = k * 64 + lane;
                if (f < NKD * 8) {
                    int dx = f >> 3, w4l = (f & 7) << 2;   // local w in wave's 32-w slab
                    float4 v;   // diagonal read so[67*(w+j)+dx]
                    v.x = so[67 * (w4l + 0) + dx];
                    v.y = so[67 * (w4l + 1) + dx];
                    v.z = so[67 * (w4l + 2) + dx];
                    v.w = so[67 * (w4l + 3) + dx];
                    *(float4*)&op[(size_t)dx * (HH * WW) + q * 32 + w4l] = v;
                }
            }
            asm volatile("s_waitcnt lgkmcnt(0)" ::: "memory");  // reads done before row1 rewrites
        }
    }
}

extern "C" void kernel_launch(void* const* d_in, const int* in_sizes, int n_in,
                              void* d_out, int out_size, void* d_ws, size_t ws_size,
                              hipStream_t stream) {
    const float* in = (const float*)d_in[0];
    float* out = (float*)d_out;
    __fp16* img_tgt = (__fp16*)d_ws;
    __fp16* img_src = (__fp16*)((char*)d_ws + (size_t)512 * IMG_HALVES * 2);

    hipLaunchKernelGGL(pack_all, dim3(1024), dim3(256), 0, stream, in, img_tgt, img_src);
    hipLaunchKernelGGL(corr_mfma, dim3(512), dim3(256), 0, stream, img_src, img_tgt, out);
}

// Round 21
// 47.594 us; speedup vs baseline: 1.1781x; 1.1781x over previous
//
#include <hip/hip_runtime.h>

#define HH 128
#define WW 128
#define CCH 128
#define NKD 21
#define RAD 10
#define ROWH 32                  // halves per row (32c) = 64B
#define CH_HALVES (148 * ROWH)   // 4736 halves per chunk (148 p-rows)
#define CH_BYTES  (CH_HALVES * 2)        // 9472 B
#define IMG_HALVES (4 * CH_HALVES)       // 18944 halves per (b,i2) = 37888 B
#define SO_STRIDE 66             // s_o row stride (floats)
#define SO_WAVE   2112           // floats per wave slab (32*66)

typedef _Float16 f16x8 __attribute__((ext_vector_type(8)));
typedef float    f32x4 __attribute__((ext_vector_type(4)));
typedef __fp16   h2f   __attribute__((ext_vector_type(2)));

union PK { uint4 u; h2f h[4]; };

// --- kernel 1: pack tgt row i2 -> f16 image [b][i2][chunk(32c)][p(148)][32 halves] ---
// XCD-affinity remap: image (b,i2) is packed on xcd = 2b + (i2>=64) — the XCD whose
// corr blocks (h0 in [i2-11, i2+10]) read it. Per-XCD image set = 2.4MB < 4MB L2.
__global__ __launch_bounds__(256)
void pack_tgt(const float* __restrict__ in, __fp16* __restrict__ img) {
    int n = blockIdx.x;                 // 512
    int xcd = n & 7, k = n >> 3;        // xcd = n%8 (dispatch round-robin)
    int b = xcd >> 1, i2 = (xcd & 1) * 64 + k;
    int tid = threadIdx.x;
    __shared__ __align__(16) char sraw[4 * CH_BYTES];   // 37888 B
    {   // zero-fill (covers p<10, p>137 pad rows)
        uint4 z = make_uint4(0, 0, 0, 0);
        uint4* sp = (uint4*)sraw;
#pragma unroll
        for (int kk = 0; kk < 9; ++kk) sp[kk * 256 + tid] = z;
        if (tid < 64) sp[9 * 256 + tid] = z;
    }
    __syncthreads();
    const float* tg = in + (size_t)(b * 2 + 1) * CCH * HH * WW + (size_t)i2 * WW;
    int w = tid & 127, half = tid >> 7;
    int p = w + RAD;                    // 10..137
#pragma unroll
    for (int c2 = 0; c2 < 2; ++c2) {
        int cc = half * 2 + c2;         // chunk 0..3 (32 channels each)
#pragma unroll
        for (int g = 0; g < 4; ++g) {   // slot g = halves c_local g*8..g*8+7
            float v[8];
#pragma unroll
            for (int j = 0; j < 8; ++j)
                v[j] = tg[(size_t)(cc * 32 + g * 8 + j) * (HH * WW) + w];
            PK q;
            q.h[0] = __builtin_amdgcn_cvt_pkrtz(v[0], v[1]);
            q.h[1] = __builtin_amdgcn_cvt_pkrtz(v[2], v[3]);
            q.h[2] = __builtin_amdgcn_cvt_pkrtz(v[4], v[5]);
            q.h[3] = __builtin_amdgcn_cvt_pkrtz(v[6], v[7]);
            *(uint4*)(sraw + (size_t)cc * CH_BYTES + p * 64 + g * 16) = q.u;
        }
    }
    __syncthreads();
    uint4* gi = (uint4*)(img + ((size_t)(b * 128 + i2)) * IMG_HALVES);   // 2368 uint4
    const uint4* si = (const uint4*)sraw;
#pragma unroll
    for (int kk = 0; kk < 9; ++kk) gi[kk * 256 + tid] = si[kk * 256 + tid];
    if (tid < 64) gi[9 * 256 + tid] = si[9 * 256 + tid];
}

// -------- kernel 2: 2-row block, dy-split-2, barrier-free, phase-rotated (R19) --------
// s_o stride 66; diagonal reads so[67*(w+j)+dx]. MFMA: a (w-rows) FIRST, bfr (p-cols)
// SECOND -> acc rows=w(4g+j), cols=p(r).
__global__ __launch_bounds__(256, 2)
void corr_mfma(const float* __restrict__ in, const __fp16* __restrict__ img_tgt,
               float* __restrict__ out) {
    int n = blockIdx.x;                 // 512
    int xcd = n & 7, idx = n >> 3;      // idx 0..63
    int u = xcd * 64 + idx;             // d-blocks of a pair adjacent on one XCD
    int d = u & 1;                      // dy-split half
    int hpair = u >> 1;                 // 0..255
    int b = hpair >> 6;                 // 0..3
    int h0 = (hpair & 63) << 1;         // even row base

    // LDS: s_srch (16KB, prologue) overlaid by s_o (33792B, wave-private slabs)
    __shared__ __align__(16) char smem[4 * SO_WAVE * 4];
    __fp16* s_srch = (__fp16*)smem;
    float*  s_o    = (float*)smem;

    int tid = threadIdx.x;
    int q = tid >> 6, lane = tid & 63, r = lane & 15, g = lane >> 4;

    const char* imgb = (const char*)(img_tgt + (size_t)(b * 128) * IMG_HALVES);
    const int hbase = h0 + d * 11;      // hp = hbase + phl_a
    const int phl0 = (2178 - h0) % 11;  // phase rotation for instantaneous L2 sharing

    // ---- pack src rows via 16KB c-half buffer; A-frags to regs ----
    f16x8 a[2][2][4];   // [row][wi][cc-group]
#pragma unroll
    for (int row = 0; row < 2; ++row) {
        const float* src = in + (size_t)(b * 2) * CCH * HH * WW + (size_t)(h0 + row) * WW;
        const float sc = 1.f / 128.f;
        int w = tid & 127, hb = tid >> 7;
#pragma unroll
        for (int chalf = 0; chalf < 2; ++chalf) {
#pragma unroll
            for (int i4 = 0; i4 < 4; ++i4) {
                int t4 = hb * 4 + i4;           // c-block within half, 0..7
                float v[8];
#pragma unroll
                for (int j = 0; j < 8; ++j)
                    v[j] = src[(size_t)(chalf * 64 + t4 * 8 + j) * (HH * WW) + w] * sc;
                PK qq;
                qq.h[0] = __builtin_amdgcn_cvt_pkrtz(v[0], v[1]);
                qq.h[1] = __builtin_amdgcn_cvt_pkrtz(v[2], v[3]);
                qq.h[2] = __builtin_amdgcn_cvt_pkrtz(v[4], v[5]);
                qq.h[3] = __builtin_amdgcn_cvt_pkrtz(v[6], v[7]);
                int slot = t4 ^ (w & 7);
                *(uint4*)&s_srch[w * 64 + slot * 8] = qq.u;
            }
            __syncthreads();
#pragma unroll
            for (int wi = 0; wi < 2; ++wi) {
                int wrow = (2 * q + wi) * 16 + r;
#pragma unroll
                for (int ksl = 0; ksl < 2; ++ksl) {
                    int slot = (ksl * 4 + g) ^ (wrow & 7);
                    a[row][wi][chalf * 2 + ksl] = *(const f16x8*)&s_srch[wrow * 64 + slot * 8];
                }
            }
            asm volatile("s_waitcnt lgkmcnt(0)" ::: "memory");
            __syncthreads();   // frags in regs everywhere before re-pack / s_o overlay
        }
    }

    // ---- static per-thread byte offsets within a chunk (clamped band rows) ----
    int off[4];
#pragma unroll
    for (int pi = 0; pi < 4; ++pi) {
        int prow = (2 * q + pi) * 16 + r;
        if (prow > 147) prow = 147;
        off[pi] = prow * 64 + g * 16;
    }

    float* outb = out + (size_t)b * (NKD * NKD) * (HH * WW) + (size_t)h0 * WW;
    float* so = s_o + q * SO_WAVE;

    auto chunk_base = [&](int phl_a) -> const char* {
        int hp = hbase + phl_a;
        if (hp < RAD || hp > 137) return nullptr;
        return imgb + (size_t)(hp - RAD) * (IMG_HALVES * 2);
    };

    // DEPTH-4 register ring; phase holds its 4 chunks in buf[0..3] (slot = cc).
    uint4 buf[4][4];
    {
        const char* cb = chunk_base(phl0);
        if (cb) {
#pragma unroll
            for (int c0 = 0; c0 < 4; ++c0)
#pragma unroll
                for (int pi = 0; pi < 4; ++pi)
                    buf[c0][pi] = *(const uint4*)(cb + c0 * CH_BYTES + off[pi]);
        }
    }

    for (int it = 0; it < 11; ++it) {
        int phl_a = phl0 + it; if (phl_a >= 11) phl_a -= 11;
        int ph_g = d * 11 + phl_a;
        int row0_on = (ph_g <= 20);
        int row1_on = (ph_g >= 1);
        bool cur_ok = (chunk_base(phl_a) != nullptr);

        const char* nxt = nullptr;
        if (it + 1 < 11) {
            int phl_n = phl_a + 1; if (phl_n >= 11) phl_n -= 11;
            nxt = chunk_base(phl_n);
        }

        f32x4 acc[2][2][3];   // [row][wi][pj]
#pragma unroll
        for (int row = 0; row < 2; ++row)
#pragma unroll
            for (int wi = 0; wi < 2; ++wi)
#pragma unroll
                for (int pj = 0; pj < 3; ++pj)
#pragma unroll
                    for (int j = 0; j < 4; ++j) acc[row][wi][pj][j] = 0.f;

#pragma unroll
        for (int cc = 0; cc < 4; ++cc) {
            f16x8 bfr[4];
#pragma unroll
            for (int pi = 0; pi < 4; ++pi)
                bfr[pi] = __builtin_bit_cast(f16x8, buf[cc][pi]);

            if (nxt) {   // prefetch next phase's cc-chunk into the slot just consumed
#pragma unroll
                for (int pi = 0; pi < 4; ++pi)
                    buf[cc][pi] = *(const uint4*)(nxt + cc * CH_BYTES + off[pi]);
            }

            if (cur_ok && row0_on) {
#pragma unroll
                for (int wi = 0; wi < 2; ++wi)
#pragma unroll
                    for (int pj = 0; pj < 3; ++pj)
                        acc[0][wi][pj] = __builtin_amdgcn_mfma_f32_16x16x32_f16(
                            a[0][wi][cc], bfr[wi + pj], acc[0][wi][pj], 0, 0, 0);
            }
            if (cur_ok && row1_on) {
#pragma unroll
                for (int wi = 0; wi < 2; ++wi)
#pragma unroll
                    for (int pj = 0; pj < 3; ++pj)
                        acc[1][wi][pj] = __builtin_amdgcn_mfma_f32_16x16x32_f16(
                            a[1][wi][cc], bfr[wi + pj], acc[1][wi][pj], 0, 0, 0);
            }
        }

        // ---- staggered epilogues: row0 dy=ph_g, row1 dy=ph_g-1 (s_o wave-private) ----
#pragma unroll
        for (int row = 0; row < 2; ++row) {
            int dy = ph_g - row;
            if ((row == 0 && !row0_on) || (row == 1 && !row1_on)) continue;
#pragma unroll
            for (int wi = 0; wi < 2; ++wi)
#pragma unroll
                for (int pj = 0; pj < 3; ++pj)
#pragma unroll
                    for (int j = 0; j < 4; ++j)
                        so[(wi * 16 + 4 * g + j) * SO_STRIDE + (wi + pj) * 16 + r]
                            = acc[row][wi][pj][j];
            asm volatile("s_waitcnt lgkmcnt(0)" ::: "memory");
            __builtin_amdgcn_sched_barrier(0);
            float* op = outb + (size_t)row * WW + (size_t)dy * NKD * (HH * WW);
#pragma unroll
            for (int k = 0; k < 3; ++k) {
                int f = k * 64 + lane;
                if (f < NKD * 8) {
                    int dx = f >> 3, w4l = (f & 7) << 2;   // local w in wave's 32-w slab
                    float4 v;   // diagonal read so[67*(w+j)+dx]
                    v.x = so[67 * (w4l + 0) + dx];
                    v.y = so[67 * (w4l + 1) + dx];
                    v.z = so[67 * (w4l + 2) + dx];
                    v.w = so[67 * (w4l + 3) + dx];
                    *(float4*)&op[(size_t)dx * (HH * WW) + q * 32 + w4l] = v;
                }
            }
            asm volatile("s_waitcnt lgkmcnt(0)" ::: "memory");  // reads done before row1 rewrites
        }
    }
}

extern "C" void kernel_launch(void* const* d_in, const int* in_sizes, int n_in,
                              void* d_out, int out_size, void* d_ws, size_t ws_size,
                              hipStream_t stream) {
    const float* in = (const float*)d_in[0];
    float* out = (float*)d_out;
    __fp16* img_tgt = (__fp16*)d_ws;

    hipLaunchKernelGGL(pack_tgt, dim3(512), dim3(256), 0, stream, in, img_tgt);
    hipLaunchKernelGGL(corr_mfma, dim3(512), dim3(256), 0, stream, in, img_tgt, out);
}